// Round 3
// baseline (99.574 us; speedup 1.0000x reference)
//
#include <hip/hip_runtime.h>

// RankingLoss: B=16384 rows, D=512 f32, L=14 labels.
// Per row i (j=i+1 mod B):
//   paired  = dot(zi[i], zt[i])
//   imp_img = dot(zi[j], zt[i])
//   imp_txt = dot(zt[j], zi[i])
//   margin  = all-equal? 0 : max(0.5, xor_cnt / or_cnt)
//   loss   += relu(imp_img - paired + margin) + relu(imp_txt - paired + margin)
// out[0] = loss / B
//
// v3: split-D. Each wave owns HALF a row (256 cols = exactly 1 float4/lane),
// register-carries over a strip of R=8 rows (reads each row once ->
// (R+1)/R * 128 MB = 144 MB logical). Wave pairs (half 0/1) share a strip;
// per-row half-sums meet in LDS with ONE barrier. 4096 waves -> 4 waves/SIMD
// (2x v2's latency hiding). Block partial -> d_ws, tiny reduce kernel.

constexpr int B = 16384;
constexpr int L = 14;
constexpr int BLOCK = 256;                  // 4 waves: 2 strips x 2 halves
constexpr int R = 8;                        // rows per strip
constexpr int STRIPS_PER_BLOCK = 2;
constexpr int GRID = B / (STRIPS_PER_BLOCK * R);   // 1024 blocks

__device__ __forceinline__ float dot4(float4 a, float4 b) {
    return a.x * b.x + a.y * b.y + a.z * b.z + a.w * b.w;
}

__global__ __launch_bounds__(BLOCK) void rank_main(
    const float* __restrict__ zi, const float* __restrict__ zt,
    const int* __restrict__ labels, float* __restrict__ ws)
{
    const int lane = threadIdx.x & 63;
    const int wv   = threadIdx.x >> 6;      // 0..3
    const int pair = wv >> 1;               // strip within block
    const int half = wv & 1;                // which 256-col half of D
    const int base = (blockIdx.x * STRIPS_PER_BLOCK + pair) * R;

    const float4* zi4 = (const float4*)zi;
    const float4* zt4 = (const float4*)zt;

    __shared__ float sdot[4][R][3];         // per-wave, per-row half-sums
    __shared__ float smar[STRIPS_PER_BLOCK][R];

    // Current row registers: 1 float4 per matrix (this wave's half of D).
    size_t o = (size_t)base * 128 + half * 64 + lane;
    float4 a = zi4[o];
    float4 b = zt4[o];
    int lab = (half == 0 && lane < L) ? labels[base * L + lane] : 0;
    float pd = dot4(a, b);                  // lane-partial paired(current)

    #pragma unroll
    for (int r = 0; r < R; ++r) {
        const int nrow = (base + r + 1) & (B - 1);
        const size_t no = (size_t)nrow * 128 + half * 64 + lane;
        const float4 na = zi4[no];
        const float4 nb = zt4[no];
        const int nlab = (half == 0 && lane < L) ? labels[nrow * L + lane] : 0;

        float s0 = pd;                      // dot(zi[i], zt[i]) partial
        float s1 = dot4(na, b);             // dot(zi[j], zt[i]) partial
        float s2 = dot4(nb, a);             // dot(zt[j], zi[i]) partial
        const float npd = dot4(na, nb);     // next paired, carried

        // Margin from label ballots (half-0 waves; lanes >= L contribute 0).
        if (half == 0) {
            const unsigned long long bor  = __ballot((lab | nlab) != 0);
            const unsigned long long bxor = __ballot((lab ^ nlab) != 0);
            if (lane == 0) {
                const int df = __popcll(bxor);
                float margin = 0.0f;
                if (df != 0)
                    margin = fmaxf(0.5f, (float)df / (float)__popcll(bor));
                smar[pair][r] = margin;
            }
        }

        // Wave-wide reduce of the three partials.
        #pragma unroll
        for (int off = 32; off > 0; off >>= 1) {
            s0 += __shfl_down(s0, off);
            s1 += __shfl_down(s1, off);
            s2 += __shfl_down(s2, off);
        }
        if (lane == 0) {
            sdot[wv][r][0] = s0;
            sdot[wv][r][1] = s1;
            sdot[wv][r][2] = s2;
        }

        a = na; b = nb; lab = nlab; pd = npd;
    }

    __syncthreads();

    // 16 rows per block: thread t < 16 combines halves + computes hinge.
    const int t = threadIdx.x;
    float hinge = 0.0f;
    if (t < STRIPS_PER_BLOCK * R) {
        const int p = t >> 3, r = t & 7;
        const float q0 = sdot[p * 2][r][0] + sdot[p * 2 + 1][r][0];
        const float q1 = sdot[p * 2][r][1] + sdot[p * 2 + 1][r][1];
        const float q2 = sdot[p * 2][r][2] + sdot[p * 2 + 1][r][2];
        const float m  = smar[p][r];
        hinge = fmaxf(q1 - q0 + m, 0.0f) + fmaxf(q2 - q0 + m, 0.0f);
    }
    #pragma unroll
    for (int off = 8; off > 0; off >>= 1) hinge += __shfl_down(hinge, off);
    if (t == 0) ws[blockIdx.x] = hinge;
}

__global__ __launch_bounds__(BLOCK) void rank_reduce(
    const float* __restrict__ ws, float* __restrict__ out)
{
    // GRID (=1024) partials; 256 threads, 4 each.
    const int t = threadIdx.x;
    float v = ws[t] + ws[t + 256] + ws[t + 512] + ws[t + 768];
    #pragma unroll
    for (int off = 32; off > 0; off >>= 1) v += __shfl_down(v, off);
    __shared__ float s[4];
    if ((t & 63) == 0) s[t >> 6] = v;
    __syncthreads();
    if (t == 0)
        out[0] = (s[0] + s[1] + s[2] + s[3]) * (1.0f / (float)B);
}

extern "C" void kernel_launch(void* const* d_in, const int* in_sizes, int n_in,
                              void* d_out, int out_size, void* d_ws, size_t ws_size,
                              hipStream_t stream) {
    const float* zi     = (const float*)d_in[0];
    const float* zt     = (const float*)d_in[1];
    const int*   labels = (const int*)d_in[2];
    float* out = (float*)d_out;
    float* ws  = (float*)d_ws;

    rank_main<<<GRID, BLOCK, 0, stream>>>(zi, zt, labels, ws);
    rank_reduce<<<1, BLOCK, 0, stream>>>(ws, out);
}